// Round 14
// baseline (105.081 us; speedup 1.0000x reference)
//
#include <hip/hip_runtime.h>
#include <hip/hip_bf16.h>

// MultiHeadAttention: B=4, S=2048, D=512, H=16, dh=32 (gfx950)
// Pipeline: proj(+fused Wo cvt) -> flash attn -> out proj.
// R14 (proj/oproj = R11 exact; attn = R13 + occupancy):
//   q-block halved to 64 rows (wave = 16 q-rows, single qi), grid 1024->2048.
//   LDS 24.6KB/block -> 6 blocks/CU co-resident = 24 waves/CU (was 16,
//   grid-capped). No launch-bounds forcing (R4 lesson). K/V staged 2x per
//   head (FETCH ~12.3->~21 MB, L2-served). Permuted-K staging, counted
//   vmcnt(2) triple-buffer, dacc ones-trick, XCD affinity all unchanged.

typedef __attribute__((ext_vector_type(8))) short bf16x8;   // 8 bf16 in 4 VGPRs
typedef __attribute__((ext_vector_type(4))) float f32x4;

#define MFMA16(a, b, c) __builtin_amdgcn_mfma_f32_16x16x32_bf16(a, b, c, 0, 0, 0)

static __device__ __forceinline__ unsigned short f2bf(float f) {
  __bf16 h = (__bf16)f;                      // RNE cvt
  union { __bf16 h; unsigned short u; } c; c.h = h; return c.u;
}
static __device__ __forceinline__ float bf2f(unsigned short u) {
  union { unsigned u; float f; } c; c.u = ((unsigned)u) << 16; return c.f;
}

// async global->LDS, 16B per lane; LDS dest must be linear (base + lane*16)
static __device__ __forceinline__ void gld_lds16(const ushort* g, ushort* l) {
  __builtin_amdgcn_global_load_lds(
      (const __attribute__((address_space(1))) unsigned int*)g,
      (__attribute__((address_space(3))) unsigned int*)l, 16, 0, 0);
}

// load 8 consecutive floats, split each into bf16 hi + bf16 residual(lo)
static __device__ __forceinline__ void load8_split(const float* p, bf16x8& hi, bf16x8& lo) {
  float4 a = *(const float4*)p;
  float4 b = *(const float4*)(p + 4);
  float v[8] = {a.x, a.y, a.z, a.w, b.x, b.y, b.z, b.w};
  #pragma unroll
  for (int j = 0; j < 8; ++j) {
    unsigned short h = f2bf(v[j]);
    hi[j] = (short)h;
    lo[j] = (short)f2bf(v[j] - bf2f(h));
  }
}

// ---------------- kernel 1(+2): projections; wcvt fused as grid tail (R11 exact) ----------------
// Qp[bh][s][e] (scaled by log2e/sqrt(32)), Kp[bh][s][e], Vt[bh][e][s]  (bf16)
__global__ __launch_bounds__(256) void proj_kernel(
    const float* __restrict__ key, const float* __restrict__ query,
    const float* __restrict__ value,
    const float* __restrict__ Wq, const float* __restrict__ Wk,
    const float* __restrict__ Wv, const float* __restrict__ Wo,
    ushort* __restrict__ Qp, ushort* __restrict__ Kp, ushort* __restrict__ Vt,
    ushort* __restrict__ Wob) {
  if (blockIdx.x >= 2048) {               // fused wcvt tail: 256 blocks
    int i = ((blockIdx.x - 2048) * 256 + threadIdx.x) * 4;
    float4 v = *(const float4*)&Wo[i];
    ushort4 o;
    o.x = f2bf(v.x); o.y = f2bf(v.y); o.z = f2bf(v.z); o.w = f2bf(v.w);
    *(ushort4*)&Wob[i] = o;
    return;
  }
  // per-wave transpose tile: stride 40 ushorts (80B rows: 16B-aligned b128 reads)
  __shared__ ushort tlds[4][16][40];
  const int tid = threadIdx.x;
  const int l = tid & 63, wid = tid >> 6;
  const int lr = l & 15, lc = l >> 4;
  const int task = blockIdx.x * 4 + wid;     // 8192 tasks: (b, s-tile16, h)
  const int h = task & 15;
  const int st = (task >> 4) & 127;
  const int b = task >> 11;
  const int bh = b * 16 + h;
  const size_t xoff = ((size_t)b * 2048 + st * 16 + lr) * 512 + h * 32 + lc * 8;
  const float ALPHA = 0.2550354039f;         // log2(e)/sqrt(32)

  #pragma unroll
  for (int t = 0; t < 3; ++t) {
    const float* x = (t == 0) ? query : (t == 1) ? key : value;
    const float* W = (t == 0) ? Wq : (t == 1) ? Wk : Wv;
    bf16x8 xh, xl;
    load8_split(x + xoff, xh, xl);
    f32x4 accs[2];
    #pragma unroll
    for (int eh = 0; eh < 2; ++eh) {
      bf16x8 wh, wl;
      load8_split(W + (size_t)(eh * 16 + lr) * 32 + lc * 8, wh, wl);
      f32x4 acc = {0.f, 0.f, 0.f, 0.f};
      acc = MFMA16(xh, wh, acc);   // hi*hi + hi*lo + lo*hi: ~fp32-accurate projection
      acc = MFMA16(xh, wl, acc);
      acc = MFMA16(xl, wh, acc);
      accs[eh] = acc;
    }
    if (t == 2) {                 // V stored transposed: Vt[bh][e][s]
      #pragma unroll
      for (int eh = 0; eh < 2; ++eh) {
        ushort4 pk;
        pk.x = f2bf(accs[eh][0]); pk.y = f2bf(accs[eh][1]);
        pk.z = f2bf(accs[eh][2]); pk.w = f2bf(accs[eh][3]);
        *(ushort4*)&Vt[((size_t)bh * 32 + eh * 16 + lr) * 2048 + st * 16 + lc * 4] = pk;
      }
    } else {
      // Q/K: per-wave LDS transpose -> one coalesced 16B store per lane
      const float scale = (t == 0) ? ALPHA : 1.0f;
      #pragma unroll
      for (int eh = 0; eh < 2; ++eh)
        #pragma unroll
        for (int r = 0; r < 4; ++r)
          tlds[wid][lc * 4 + r][eh * 16 + lr] = f2bf(accs[eh][r] * scale);
      // wave-internal RAW; compiler inserts counted lgkmcnt
      bf16x8 row = *(const bf16x8*)&tlds[wid][l >> 2][(l & 3) * 8];
      ushort* dst = ((t == 0) ? Qp : Kp) +
                    ((size_t)bh * 2048 + st * 16 + (l >> 2)) * 32 + (l & 3) * 8;
      *(bf16x8*)dst = row;
    }
  }
}

// ---------------- kernel 3: attention ----------------
// grid 2048. XCD-affinity decode: xcd = bid&7, idx = bid>>3 (0..255);
// bh = xcd*8 + idx/32, qblk = idx%32 -> all 32 q-blocks of a bh on one XCD.
// 4 waves * 16 q-rows (q0 = qblk*64 + w*16). Swapped QK with PERMUTED K rows:
// physical row m holds logical key perm(m) = (m&32)|((m&12)<<1)|((m&16)>>2)|(m&3),
// so after QK+exp lane (lr,lc) holds P[q=lr] for logical k = kc*32+lc*8+b4*4+r
// == exactly its PV A-fragment -> P stays in registers. No max-subtraction
// (logits in log2 units, |s|<~3). K/V tiles staged to LDS (3 buffers); stage
// t+2 at tile t; per-tile wait = vmcnt(2) (tail: vmcnt(0)) + raw s_barrier.
__global__ __launch_bounds__(256) void attn_kernel(
    const ushort* __restrict__ Qp, const ushort* __restrict__ Kp,
    const ushort* __restrict__ Vt, ushort* __restrict__ Cb) {
  __shared__ ushort kbuf[3][2048];     // [64 keys][32 dh], row-permuted + XOR-swizzled
  __shared__ ushort vbuf[3][2048];     // [32 e][64 keys], XOR-swizzled
  const int tid = threadIdx.x;
  const int l = tid & 63;
  const int lr = l & 15, lc = l >> 4;
  const int xcd = blockIdx.x & 7, idx = blockIdx.x >> 3;
  const int bh = xcd * 8 + (idx >> 5);
  const int qblk = idx & 31;
  const int b = bh >> 4, h = bh & 15;
  const int q0 = qblk * 64 + (tid >> 6) * 16;

  const ushort* Qb = Qp + (size_t)bh * 2048 * 32;
  const ushort* Kb = Kp + (size_t)bh * 2048 * 32;
  const ushort* Vb = Vt + (size_t)bh * 32 * 2048;

  // K staging source: physical 16B unit tid <- XOR-involution -> (row m, part pp)
  // -> logical row perm(m). Inverse-swizzled + permuted GLOBAL source, linear
  // LDS dest (both-sides rule).
  const int s = tid ^ ((tid >> 3) & 7);            // involution on 16B units
  const int m = s >> 2, pp = s & 3;
  const int g = (m & 32) | ((m & 12) << 1) | ((m & 16) >> 2) | (m & 3);
  const ushort* kg_src = Kb + (size_t)(g * 4 + pp) * 8;     // +k0*32 per tile
  const ushort* vg_src = Vb + (size_t)(tid >> 3) * 2048 +
                         (((tid & 7) ^ ((tid >> 3) & 7)) * 8);   // +k0 per tile

  // hoisted swizzled read offsets (ushort units): unit v -> lds unit v^((v>>3)&7)
  int koff[4];
  #pragma unroll
  for (int kg = 0; kg < 4; ++kg) {
    int v = (kg * 16 + lr) * 4 + lc;
    v ^= (v >> 3) & 7;
    koff[kg] = v * 8;
  }
  int voff[2][2];
  #pragma unroll
  for (int kc = 0; kc < 2; ++kc)
    #pragma unroll
    for (int eh = 0; eh < 2; ++eh) {
      int v = (eh * 16 + lr) * 8 + kc * 4 + lc;
      v ^= (v >> 3) & 7;
      voff[kc][eh] = v * 8;
    }

  const bf16x8 qf = *(const bf16x8*)&Qb[(size_t)(q0 + lr) * 32 + lc * 8];

  bf16x8 ones;
  #pragma unroll
  for (int j = 0; j < 8; ++j) ones[j] = (short)0x3F80;   // bf16 1.0

  f32x4 octx[2] = {};
  f32x4 dacc = {};                     // rowsum(P) per q=lc*4+r, octx layout
  const f32x4 zero = {0.f, 0.f, 0.f, 0.f};

  // prologue: stage tiles 0 and 1; wait for tile 0 (leave tile 1 in flight)
  gld_lds16(kg_src, &kbuf[0][tid * 8]);
  gld_lds16(vg_src, &vbuf[0][tid * 8]);
  gld_lds16(kg_src + (size_t)64 * 32, &kbuf[1][tid * 8]);
  gld_lds16(vg_src + 64, &vbuf[1][tid * 8]);
  asm volatile("s_waitcnt vmcnt(2)" ::: "memory");
  __builtin_amdgcn_s_barrier();

  int cur = 0, nx2 = 2;
  for (int kt = 0; kt < 32; ++kt) {
    // stage tile kt+2 into the buffer freed at the last barrier
    if (kt < 30) {
      const int k0n = (kt + 2) * 64;
      gld_lds16(kg_src + (size_t)k0n * 32, &kbuf[nx2][tid * 8]);
      gld_lds16(vg_src + k0n, &vbuf[nx2][tid * 8]);
    }

    const ushort* kb = kbuf[cur];
    const ushort* vb = vbuf[cur];
    bf16x8 kf[4];
    #pragma unroll
    for (int kg = 0; kg < 4; ++kg)
      kf[kg] = *(const bf16x8*)&kb[koff[kg]];
    bf16x8 vf[2][2];
    #pragma unroll
    for (int kc = 0; kc < 2; ++kc)
      #pragma unroll
      for (int eh = 0; eh < 2; ++eh)
        vf[kc][eh] = *(const bf16x8*)&vb[voff[kc][eh]];

    f32x4 sc[4];
    #pragma unroll
    for (int kg = 0; kg < 4; ++kg)
      sc[kg] = MFMA16(kf[kg], qf, zero);   // D[m=permuted k][n=q]
    // P-fragment built entirely in registers: element j of the PV A-frag is
    // exp(sc[2kc + (j>>2)][j&3]) -- consecutive logical k by construction.
    #pragma unroll
    for (int kc = 0; kc < 2; ++kc) {
      bf16x8 pa;
      #pragma unroll
      for (int r = 0; r < 4; ++r) {
        pa[r]     = (short)f2bf(__builtin_amdgcn_exp2f(sc[2 * kc][r]));
        pa[4 + r] = (short)f2bf(__builtin_amdgcn_exp2f(sc[2 * kc + 1][r]));
      }
      #pragma unroll
      for (int eh = 0; eh < 2; ++eh)
        octx[eh] = MFMA16(pa, vf[kc][eh], octx[eh]);
      dacc = MFMA16(pa, ones, dacc);   // row-sum of same rounded P
    }

    // counted wait: retire tile kt+1's loads only (tail drains everything)
    if (kt < 30) {
      asm volatile("s_waitcnt vmcnt(2)" ::: "memory");
    } else {
      asm volatile("s_waitcnt vmcnt(0)" ::: "memory");
    }
    __builtin_amdgcn_s_barrier();
    cur = (cur == 2) ? 0 : cur + 1;
    nx2 = (nx2 == 2) ? 0 : nx2 + 1;
  }

  // normalize (shuffle-free: dacc rows == octx rows) and store ctx bf16
  float inv[4];
  #pragma unroll
  for (int r = 0; r < 4; ++r)
    inv[r] = 1.0f / dacc[r];
  #pragma unroll
  for (int eh = 0; eh < 2; ++eh)
    #pragma unroll
    for (int r = 0; r < 4; ++r) {
      float v = octx[eh][r] * inv[r];
      Cb[((size_t)b * 2048 + q0 + lc * 4 + r) * 512 + h * 32 + eh * 16 + lr] = f2bf(v);
    }
}

// ---------------- kernel 4: out = ctx @ Wo^T + bo (R11 exact) ----------------
// grid 256: bid>>1 = 64-row q-tile, bid&1 = 256-col n-half; each wave 64x64.
__global__ __launch_bounds__(256) void oproj_kernel(
    const ushort* __restrict__ Cb, const ushort* __restrict__ Wob,
    const float* __restrict__ bo, float* __restrict__ out) {
  const int tid = threadIdx.x;
  const int l = tid & 63, w = tid >> 6;
  const int lr = l & 15, lc = l >> 4;
  const int qt = blockIdx.x >> 1;
  const int nt = blockIdx.x & 1;
  const int r0 = qt * 64;
  const int n0 = nt * 256 + w * 64;

  f32x4 acc[4][4] = {};
  for (int kk = 0; kk < 16; ++kk) {
    const int k0 = kk * 32;
    bf16x8 af[4], bf[4];
    #pragma unroll
    for (int i = 0; i < 4; ++i)
      af[i] = *(const bf16x8*)&Cb[(size_t)(r0 + i * 16 + lr) * 512 + k0 + lc * 8];
    #pragma unroll
    for (int j = 0; j < 4; ++j)
      bf[j] = *(const bf16x8*)&Wob[(size_t)(n0 + j * 16 + lr) * 512 + k0 + lc * 8];
    #pragma unroll
    for (int i = 0; i < 4; ++i)
      #pragma unroll
      for (int j = 0; j < 4; ++j)
        acc[i][j] = MFMA16(af[i], bf[j], acc[i][j]);
  }
  #pragma unroll
  for (int j = 0; j < 4; ++j) {
    float bias = bo[n0 + j * 16 + lr];
    #pragma unroll
    for (int i = 0; i < 4; ++i)
      #pragma unroll
      for (int r = 0; r < 4; ++r)
        out[(size_t)(r0 + i * 16 + lc * 4 + r) * 512 + n0 + j * 16 + lr] =
            acc[i][j][r] + bias;
  }
}

extern "C" void kernel_launch(void* const* d_in, const int* in_sizes, int n_in,
                              void* d_out, int out_size, void* d_ws, size_t ws_size,
                              hipStream_t stream) {
  (void)in_sizes; (void)n_in; (void)out_size; (void)ws_size;
  const float* key   = (const float*)d_in[0];
  const float* query = (const float*)d_in[1];
  const float* value = (const float*)d_in[2];
  const float* Wq    = (const float*)d_in[3];
  const float* Wk    = (const float*)d_in[4];
  const float* Wv    = (const float*)d_in[5];
  const float* Wo    = (const float*)d_in[6];
  const float* bo    = (const float*)d_in[7];
  float* out = (float*)d_out;

  // workspace layout (bf16/ushort elements): Qp, Kp, Vt, Cb (4*16*2048*32 each), Wob (512*512)
  const size_t NT = (size_t)4 * 16 * 2048 * 32;   // 4,194,304
  ushort* ws  = (ushort*)d_ws;
  ushort* Qp  = ws;
  ushort* Kp  = Qp + NT;
  ushort* Vt  = Kp + NT;
  ushort* Cb  = Vt + NT;
  ushort* Wob = Cb + NT;                           // total ~34.1 MB

  hipLaunchKernelGGL(proj_kernel, dim3(2304), dim3(256), 0, stream,
                     key, query, value, Wq, Wk, Wv, Wo, Qp, Kp, Vt, Wob);
  hipLaunchKernelGGL(attn_kernel, dim3(2048), dim3(256), 0, stream, Qp, Kp, Vt, Cb);
  hipLaunchKernelGGL(oproj_kernel, dim3(256), dim3(256), 0, stream, Cb, Wob, bo, out);
}

// Round 15
// 89.999 us; speedup vs baseline: 1.1676x; 1.1676x over previous
//
#include <hip/hip_runtime.h>
#include <hip/hip_bf16.h>

// MultiHeadAttention: B=4, S=2048, D=512, H=16, dh=32 (gfx950)
// Pipeline: proj(+fused Wo cvt) -> flash attn -> out proj.
// R15 (proj/oproj = R11 exact; attn = R13 compute, amortized staging):
//   Blocks grow to 512 threads / 8 waves x 32 q-rows (256 q-rows/block),
//   grid 512. One K/V staging serves 8 waves (R13: 4): waves 0-3 stage K,
//   waves 4-7 stage V -> 1 DMA/thread/tile, per-wave wait vmcnt(1).
//   Barriers per q-row and staging issue both halve. R14 lesson: occupancy
//   was not the limiter; per-barrier compute was.

typedef __attribute__((ext_vector_type(8))) short bf16x8;   // 8 bf16 in 4 VGPRs
typedef __attribute__((ext_vector_type(4))) float f32x4;

#define MFMA16(a, b, c) __builtin_amdgcn_mfma_f32_16x16x32_bf16(a, b, c, 0, 0, 0)

static __device__ __forceinline__ unsigned short f2bf(float f) {
  __bf16 h = (__bf16)f;                      // RNE cvt
  union { __bf16 h; unsigned short u; } c; c.h = h; return c.u;
}
static __device__ __forceinline__ float bf2f(unsigned short u) {
  union { unsigned u; float f; } c; c.u = ((unsigned)u) << 16; return c.f;
}

// async global->LDS, 16B per lane; LDS dest must be linear (base + lane*16)
static __device__ __forceinline__ void gld_lds16(const ushort* g, ushort* l) {
  __builtin_amdgcn_global_load_lds(
      (const __attribute__((address_space(1))) unsigned int*)g,
      (__attribute__((address_space(3))) unsigned int*)l, 16, 0, 0);
}

// load 8 consecutive floats, split each into bf16 hi + bf16 residual(lo)
static __device__ __forceinline__ void load8_split(const float* p, bf16x8& hi, bf16x8& lo) {
  float4 a = *(const float4*)p;
  float4 b = *(const float4*)(p + 4);
  float v[8] = {a.x, a.y, a.z, a.w, b.x, b.y, b.z, b.w};
  #pragma unroll
  for (int j = 0; j < 8; ++j) {
    unsigned short h = f2bf(v[j]);
    hi[j] = (short)h;
    lo[j] = (short)f2bf(v[j] - bf2f(h));
  }
}

// ---------------- kernel 1(+2): projections; wcvt fused as grid tail (R11 exact) ----------------
// Qp[bh][s][e] (scaled by log2e/sqrt(32)), Kp[bh][s][e], Vt[bh][e][s]  (bf16)
__global__ __launch_bounds__(256) void proj_kernel(
    const float* __restrict__ key, const float* __restrict__ query,
    const float* __restrict__ value,
    const float* __restrict__ Wq, const float* __restrict__ Wk,
    const float* __restrict__ Wv, const float* __restrict__ Wo,
    ushort* __restrict__ Qp, ushort* __restrict__ Kp, ushort* __restrict__ Vt,
    ushort* __restrict__ Wob) {
  if (blockIdx.x >= 2048) {               // fused wcvt tail: 256 blocks
    int i = ((blockIdx.x - 2048) * 256 + threadIdx.x) * 4;
    float4 v = *(const float4*)&Wo[i];
    ushort4 o;
    o.x = f2bf(v.x); o.y = f2bf(v.y); o.z = f2bf(v.z); o.w = f2bf(v.w);
    *(ushort4*)&Wob[i] = o;
    return;
  }
  // per-wave transpose tile: stride 40 ushorts (80B rows: 16B-aligned b128 reads)
  __shared__ ushort tlds[4][16][40];
  const int tid = threadIdx.x;
  const int l = tid & 63, wid = tid >> 6;
  const int lr = l & 15, lc = l >> 4;
  const int task = blockIdx.x * 4 + wid;     // 8192 tasks: (b, s-tile16, h)
  const int h = task & 15;
  const int st = (task >> 4) & 127;
  const int b = task >> 11;
  const int bh = b * 16 + h;
  const size_t xoff = ((size_t)b * 2048 + st * 16 + lr) * 512 + h * 32 + lc * 8;
  const float ALPHA = 0.2550354039f;         // log2(e)/sqrt(32)

  #pragma unroll
  for (int t = 0; t < 3; ++t) {
    const float* x = (t == 0) ? query : (t == 1) ? key : value;
    const float* W = (t == 0) ? Wq : (t == 1) ? Wk : Wv;
    bf16x8 xh, xl;
    load8_split(x + xoff, xh, xl);
    f32x4 accs[2];
    #pragma unroll
    for (int eh = 0; eh < 2; ++eh) {
      bf16x8 wh, wl;
      load8_split(W + (size_t)(eh * 16 + lr) * 32 + lc * 8, wh, wl);
      f32x4 acc = {0.f, 0.f, 0.f, 0.f};
      acc = MFMA16(xh, wh, acc);   // hi*hi + hi*lo + lo*hi: ~fp32-accurate projection
      acc = MFMA16(xh, wl, acc);
      acc = MFMA16(xl, wh, acc);
      accs[eh] = acc;
    }
    if (t == 2) {                 // V stored transposed: Vt[bh][e][s]
      #pragma unroll
      for (int eh = 0; eh < 2; ++eh) {
        ushort4 pk;
        pk.x = f2bf(accs[eh][0]); pk.y = f2bf(accs[eh][1]);
        pk.z = f2bf(accs[eh][2]); pk.w = f2bf(accs[eh][3]);
        *(ushort4*)&Vt[((size_t)bh * 32 + eh * 16 + lr) * 2048 + st * 16 + lc * 4] = pk;
      }
    } else {
      // Q/K: per-wave LDS transpose -> one coalesced 16B store per lane
      const float scale = (t == 0) ? ALPHA : 1.0f;
      #pragma unroll
      for (int eh = 0; eh < 2; ++eh)
        #pragma unroll
        for (int r = 0; r < 4; ++r)
          tlds[wid][lc * 4 + r][eh * 16 + lr] = f2bf(accs[eh][r] * scale);
      // wave-internal RAW; compiler inserts counted lgkmcnt
      bf16x8 row = *(const bf16x8*)&tlds[wid][l >> 2][(l & 3) * 8];
      ushort* dst = ((t == 0) ? Qp : Kp) +
                    ((size_t)bh * 2048 + st * 16 + (l >> 2)) * 32 + (l & 3) * 8;
      *(bf16x8*)dst = row;
    }
  }
}

// ---------------- kernel 3: attention ----------------
// grid 512, block 512 (8 waves x 32 q-rows = 256 q-rows/block).
// XCD-affinity: xcd = bid&7, idx = bid>>3 (0..63); bh = xcd*8 + idx/8,
// qblk = idx%8 -> all 8 q-blocks of a bh on one XCD.
// Swapped QK with PERMUTED K rows: physical row m holds logical key
// perm(m) = (m&32)|((m&12)<<1)|((m&16)>>2)|(m&3); after QK+exp lane (lr,lc)
// holds P[q=lr] for logical k = kc*32+lc*8+b4*4+r == its PV A-fragment ->
// P stays in registers. No max-subtraction (logits in log2 units, |s|<~3).
// K/V staged to LDS (3 buffers kv[3][4096]: K in [0,2048), V in [2048,4096)):
// waves 0-3 stage K, waves 4-7 stage V (1 DMA/thread/tile); stage t+2 at
// tile t; per-tile wait = vmcnt(1) (tail: vmcnt(0)) + raw s_barrier.
__global__ __launch_bounds__(512) void attn_kernel(
    const ushort* __restrict__ Qp, const ushort* __restrict__ Kp,
    const ushort* __restrict__ Vt, ushort* __restrict__ Cb) {
  __shared__ ushort kv[3][4096];
  const int tid = threadIdx.x;
  const int l = tid & 63, w = tid >> 6;
  const int lr = l & 15, lc = l >> 4;
  const int xcd = blockIdx.x & 7, idx = blockIdx.x >> 3;
  const int bh = xcd * 8 + (idx >> 3);
  const int qblk = idx & 7;
  const int b = bh >> 4, h = bh & 15;
  const int q0 = qblk * 256 + w * 32;

  const ushort* Qb = Qp + (size_t)bh * 2048 * 32;
  const ushort* Kb = Kp + (size_t)bh * 2048 * 32;
  const ushort* Vb = Vt + (size_t)bh * 32 * 2048;

  // staging assignment: threads 0-255 stage K (row-permuted + XOR-swizzled
  // global source, linear LDS dest); threads 256-511 stage V (XOR-swizzled).
  const bool stageK = tid < 256;
  const int st = stageK ? tid : tid - 256;
  const int si = st ^ ((st >> 3) & 7);             // involution on 16B units
  const int m = si >> 2, pp = si & 3;
  const int g = (m & 32) | ((m & 12) << 1) | ((m & 16) >> 2) | (m & 3);
  const ushort* src0 = stageK
      ? Kb + (size_t)(g * 4 + pp) * 8
      : Vb + (size_t)(st >> 3) * 2048 + (((st & 7) ^ ((st >> 3) & 7)) * 8);
  const size_t sstep = stageK ? (size_t)64 * 32 : (size_t)64;  // ushorts/tile
  const int dofs = (stageK ? 0 : 2048) + st * 8;

  // hoisted swizzled read offsets (ushort units): unit v -> lds unit v^((v>>3)&7)
  int koff[4];
  #pragma unroll
  for (int kg = 0; kg < 4; ++kg) {
    int v = (kg * 16 + lr) * 4 + lc;
    v ^= (v >> 3) & 7;
    koff[kg] = v * 8;
  }
  int voff[2][2];
  #pragma unroll
  for (int kc = 0; kc < 2; ++kc)
    #pragma unroll
    for (int eh = 0; eh < 2; ++eh) {
      int v = (eh * 16 + lr) * 8 + kc * 4 + lc;
      v ^= (v >> 3) & 7;
      voff[kc][eh] = 2048 + v * 8;
    }

  bf16x8 qf[2];
  qf[0] = *(const bf16x8*)&Qb[(size_t)(q0 + lr) * 32 + lc * 8];
  qf[1] = *(const bf16x8*)&Qb[(size_t)(q0 + 16 + lr) * 32 + lc * 8];

  bf16x8 ones;
  #pragma unroll
  for (int j = 0; j < 8; ++j) ones[j] = (short)0x3F80;   // bf16 1.0

  f32x4 octx[2][2] = {};
  f32x4 dacc[2] = {};                  // rowsum(P) per q=lc*4+r, octx layout
  const f32x4 zero = {0.f, 0.f, 0.f, 0.f};

  // prologue: stage tiles 0 and 1 (1 DMA each); wait tile 0, leave 1 in flight
  gld_lds16(src0, &kv[0][dofs]);
  gld_lds16(src0 + sstep, &kv[1][dofs]);
  asm volatile("s_waitcnt vmcnt(1)" ::: "memory");
  __builtin_amdgcn_s_barrier();

  int cur = 0, nx2 = 2;
  for (int kt = 0; kt < 32; ++kt) {
    // stage tile kt+2 into the buffer freed at the last barrier
    if (kt < 30)
      gld_lds16(src0 + (size_t)(kt + 2) * sstep, &kv[nx2][dofs]);

    const ushort* kb = kv[cur];
    bf16x8 kf[4];
    #pragma unroll
    for (int kg = 0; kg < 4; ++kg)
      kf[kg] = *(const bf16x8*)&kb[koff[kg]];
    bf16x8 vf[2][2];
    #pragma unroll
    for (int kc = 0; kc < 2; ++kc)
      #pragma unroll
      for (int eh = 0; eh < 2; ++eh)
        vf[kc][eh] = *(const bf16x8*)&kb[voff[kc][eh]];

    #pragma unroll
    for (int qi = 0; qi < 2; ++qi) {
      f32x4 sc[4];
      #pragma unroll
      for (int kg = 0; kg < 4; ++kg)
        sc[kg] = MFMA16(kf[kg], qf[qi], zero);   // D[m=permuted k][n=q]
      // P-fragment built entirely in registers: element j of the PV A-frag is
      // exp(sc[2kc + (j>>2)][j&3]) -- consecutive logical k by construction.
      #pragma unroll
      for (int kc = 0; kc < 2; ++kc) {
        bf16x8 pa;
        #pragma unroll
        for (int r = 0; r < 4; ++r) {
          pa[r]     = (short)f2bf(__builtin_amdgcn_exp2f(sc[2 * kc][r]));
          pa[4 + r] = (short)f2bf(__builtin_amdgcn_exp2f(sc[2 * kc + 1][r]));
        }
        #pragma unroll
        for (int eh = 0; eh < 2; ++eh)
          octx[qi][eh] = MFMA16(pa, vf[kc][eh], octx[qi][eh]);
        dacc[qi] = MFMA16(pa, ones, dacc[qi]);   // row-sum of same rounded P
      }
    }

    // counted wait: retire own tile-(kt+1) DMA only (tail drains everything)
    if (kt < 30) {
      asm volatile("s_waitcnt vmcnt(1)" ::: "memory");
    } else {
      asm volatile("s_waitcnt vmcnt(0)" ::: "memory");
    }
    __builtin_amdgcn_s_barrier();
    cur = (cur == 2) ? 0 : cur + 1;
    nx2 = (nx2 == 2) ? 0 : nx2 + 1;
  }

  // normalize (shuffle-free: dacc rows == octx rows) and store ctx bf16
  #pragma unroll
  for (int qi = 0; qi < 2; ++qi) {
    float inv[4];
    #pragma unroll
    for (int r = 0; r < 4; ++r)
      inv[r] = 1.0f / dacc[qi][r];
    #pragma unroll
    for (int eh = 0; eh < 2; ++eh)
      #pragma unroll
      for (int r = 0; r < 4; ++r) {
        float v = octx[qi][eh][r] * inv[r];
        Cb[((size_t)b * 2048 + q0 + qi * 16 + lc * 4 + r) * 512 + h * 32 + eh * 16 + lr] =
            f2bf(v);
      }
  }
}

// ---------------- kernel 4: out = ctx @ Wo^T + bo (R11 exact) ----------------
// grid 256: bid>>1 = 64-row q-tile, bid&1 = 256-col n-half; each wave 64x64.
__global__ __launch_bounds__(256) void oproj_kernel(
    const ushort* __restrict__ Cb, const ushort* __restrict__ Wob,
    const float* __restrict__ bo, float* __restrict__ out) {
  const int tid = threadIdx.x;
  const int l = tid & 63, w = tid >> 6;
  const int lr = l & 15, lc = l >> 4;
  const int qt = blockIdx.x >> 1;
  const int nt = blockIdx.x & 1;
  const int r0 = qt * 64;
  const int n0 = nt * 256 + w * 64;

  f32x4 acc[4][4] = {};
  for (int kk = 0; kk < 16; ++kk) {
    const int k0 = kk * 32;
    bf16x8 af[4], bf[4];
    #pragma unroll
    for (int i = 0; i < 4; ++i)
      af[i] = *(const bf16x8*)&Cb[(size_t)(r0 + i * 16 + lr) * 512 + k0 + lc * 8];
    #pragma unroll
    for (int j = 0; j < 4; ++j)
      bf[j] = *(const bf16x8*)&Wob[(size_t)(n0 + j * 16 + lr) * 512 + k0 + lc * 8];
    #pragma unroll
    for (int i = 0; i < 4; ++i)
      #pragma unroll
      for (int j = 0; j < 4; ++j)
        acc[i][j] = MFMA16(af[i], bf[j], acc[i][j]);
  }
  #pragma unroll
  for (int j = 0; j < 4; ++j) {
    float bias = bo[n0 + j * 16 + lr];
    #pragma unroll
    for (int i = 0; i < 4; ++i)
      #pragma unroll
      for (int r = 0; r < 4; ++r)
        out[(size_t)(r0 + i * 16 + lc * 4 + r) * 512 + n0 + j * 16 + lr] =
            acc[i][j][r] + bias;
  }
}

extern "C" void kernel_launch(void* const* d_in, const int* in_sizes, int n_in,
                              void* d_out, int out_size, void* d_ws, size_t ws_size,
                              hipStream_t stream) {
  (void)in_sizes; (void)n_in; (void)out_size; (void)ws_size;
  const float* key   = (const float*)d_in[0];
  const float* query = (const float*)d_in[1];
  const float* value = (const float*)d_in[2];
  const float* Wq    = (const float*)d_in[3];
  const float* Wk    = (const float*)d_in[4];
  const float* Wv    = (const float*)d_in[5];
  const float* Wo    = (const float*)d_in[6];
  const float* bo    = (const float*)d_in[7];
  float* out = (float*)d_out;

  // workspace layout (bf16/ushort elements): Qp, Kp, Vt, Cb (4*16*2048*32 each), Wob (512*512)
  const size_t NT = (size_t)4 * 16 * 2048 * 32;   // 4,194,304
  ushort* ws  = (ushort*)d_ws;
  ushort* Qp  = ws;
  ushort* Kp  = Qp + NT;
  ushort* Vt  = Kp + NT;
  ushort* Cb  = Vt + NT;
  ushort* Wob = Cb + NT;                           // total ~34.1 MB

  hipLaunchKernelGGL(proj_kernel, dim3(2304), dim3(256), 0, stream,
                     key, query, value, Wq, Wk, Wv, Wo, Qp, Kp, Vt, Wob);
  hipLaunchKernelGGL(attn_kernel, dim3(512), dim3(512), 0, stream, Qp, Kp, Vt, Cb);
  hipLaunchKernelGGL(oproj_kernel, dim3(256), dim3(256), 0, stream, Cb, Wob, bo, out);
}